// Round 2
// baseline (1346.305 us; speedup 1.0000x reference)
//
#include <hip/hip_runtime.h>
#include <hip/hip_bf16.h>

// ---------------------------------------------------------------------------
// Transformer encoder layer (post-norm) on MI355X.
// ALL inputs/outputs are float32 (per reference). Internally: weights and
// GEMM A-operands cast to bf16 for MFMA; f32 accumulation everywhere.
// S=1024 B=8 D=512 H=8 HD=64 DFF=2048, N = S*B = 8192 rows.
// ---------------------------------------------------------------------------

#define S_LEN 1024
#define BATCH 8
#define DMODEL 512
#define NHEAD 8
#define HDIM 64
#define DFF 2048
#define NROWS (S_LEN * BATCH)   // 8192

typedef __bf16 bf16x8 __attribute__((ext_vector_type(8)));
typedef float f32x4 __attribute__((ext_vector_type(4)));

// ---------------------------------------------------------------------------
// f32 -> bf16 cast (weights). n divisible by 4.
// ---------------------------------------------------------------------------
__global__ __launch_bounds__(256)
void cast_kernel(const float* __restrict__ in, __hip_bfloat16* __restrict__ out, int n) {
    int i = (blockIdx.x * blockDim.x + threadIdx.x) * 4;
    if (i + 3 < n) {
        float4 v = *(const float4*)(in + i);
        out[i + 0] = __float2bfloat16(v.x);
        out[i + 1] = __float2bfloat16(v.y);
        out[i + 2] = __float2bfloat16(v.z);
        out[i + 3] = __float2bfloat16(v.w);
    }
}

// ---------------------------------------------------------------------------
// Relative-position bias table: bias_tab[rel + 1023][h], rel = k - q.
// Buckets via exact integer thresholds (8*16^(j/8)); boundaries at rp=16,32,64
// verified against correctly-rounded fp32 log arithmetic (16->10, 32->12, 64->14).
// ---------------------------------------------------------------------------
__global__ void bias_table_kernel(const float* __restrict__ rel_emb,
                                  float* __restrict__ bias_tab) {
    int idx = blockIdx.x * blockDim.x + threadIdx.x;
    if (idx >= 2 * S_LEN - 1) return;
    int rel = idx - (S_LEN - 1);          // -1023 .. 1023
    int bucket = (rel > 0) ? 16 : 0;
    int rp = rel < 0 ? -rel : rel;
    int v;
    if (rp < 8)          v = rp;
    else if (rp < 12)    v = 8;
    else if (rp < 16)    v = 9;
    else if (rp < 23)    v = 10;
    else if (rp < 32)    v = 11;
    else if (rp < 46)    v = 12;
    else if (rp < 64)    v = 13;
    else if (rp < 91)    v = 14;
    else                 v = 15;
    bucket += v;
    for (int h = 0; h < NHEAD; ++h)
        bias_tab[idx * NHEAD + h] = rel_emb[bucket * NHEAD + h];
}

// ---------------------------------------------------------------------------
// NT GEMM: Y[n][m] = sum_k A[n][k] * W[m][k] + bias[m]
// A: [N][K] (f32 if A_F32 else bf16) row-major; W: [M][K] bf16 row-major.
// Block = 256 thr = 4 waves; block tile 64x64; wave computes 16 rows x 64 cols
// via 4 accumulators of mfma_f32_16x16x32_bf16.
// Fragment layouts (learn_hip m89/m91-verified):
//   A: lane holds A[m=lane&15][k0 + (lane>>4)*8 + j], j=0..7  (16B contiguous)
//   B: lane holds W[n=lane&15][k...]                           (16B contiguous)
//   D: acc[r] -> row = (lane>>4)*4 + r, col = lane&15
// ---------------------------------------------------------------------------
template <bool A_F32, bool RELU, bool OUT_BF16>
__global__ __launch_bounds__(256)
void gemm_nt(const void* __restrict__ Av,
             const __hip_bfloat16* __restrict__ W,
             const float* __restrict__ bias,
             void* __restrict__ outv,
             int N, int M, int K) {
    const int wave = threadIdx.x >> 6;
    const int lane = threadIdx.x & 63;
    const int m16  = lane & 15;
    const int quad = lane >> 4;
    const int row0 = blockIdx.y * 64 + wave * 16;
    const int col0 = blockIdx.x * 64;

    const __bf16* Wp = (const __bf16*)W + (size_t)(col0 + m16) * K + quad * 8;
    const size_t wstride = (size_t)16 * K;

    f32x4 acc[4] = {f32x4{0,0,0,0}, f32x4{0,0,0,0}, f32x4{0,0,0,0}, f32x4{0,0,0,0}};

    if (A_F32) {
        const float* Ap = (const float*)Av + (size_t)(row0 + m16) * K + quad * 8;
        for (int k0 = 0; k0 < K; k0 += 32) {
            float4 lo = *(const float4*)(Ap + k0);
            float4 hi = *(const float4*)(Ap + k0 + 4);
            union { bf16x8 v; __hip_bfloat16 e[8]; } u;
            u.e[0] = __float2bfloat16(lo.x); u.e[1] = __float2bfloat16(lo.y);
            u.e[2] = __float2bfloat16(lo.z); u.e[3] = __float2bfloat16(lo.w);
            u.e[4] = __float2bfloat16(hi.x); u.e[5] = __float2bfloat16(hi.y);
            u.e[6] = __float2bfloat16(hi.z); u.e[7] = __float2bfloat16(hi.w);
#pragma unroll
            for (int c = 0; c < 4; ++c) {
                bf16x8 bfr = *(const bf16x8*)(Wp + c * wstride + k0);
                acc[c] = __builtin_amdgcn_mfma_f32_16x16x32_bf16(u.v, bfr, acc[c], 0, 0, 0);
            }
        }
    } else {
        const __bf16* Ap = (const __bf16*)Av + (size_t)(row0 + m16) * K + quad * 8;
        for (int k0 = 0; k0 < K; k0 += 32) {
            bf16x8 a = *(const bf16x8*)(Ap + k0);
#pragma unroll
            for (int c = 0; c < 4; ++c) {
                bf16x8 bfr = *(const bf16x8*)(Wp + c * wstride + k0);
                acc[c] = __builtin_amdgcn_mfma_f32_16x16x32_bf16(a, bfr, acc[c], 0, 0, 0);
            }
        }
    }

#pragma unroll
    for (int c = 0; c < 4; ++c) {
        int col = col0 + c * 16 + m16;
        float bv = bias[col];
#pragma unroll
        for (int r = 0; r < 4; ++r) {
            int row = row0 + quad * 4 + r;
            float v = acc[c][r] + bv;
            if (RELU) v = fmaxf(v, 0.f);
            if (OUT_BF16) ((__hip_bfloat16*)outv)[(size_t)row * M + col] = __float2bfloat16(v);
            else          ((float*)outv)[(size_t)row * M + col] = v;
        }
    }
}

// ---------------------------------------------------------------------------
// Flash-style attention (vector ALU).
// Grid: (S/16 q-tiles, B*H). Block 256 threads.
// qkv (bf16) layout: row n = s*8 + b, cols: q = h*64+hd, k = 512+..., v = 1024+...
// Online softmax over 2 chunks of 512 keys. q pre-scaled by 1/sqrt(64)=0.125.
// ---------------------------------------------------------------------------
#define SQ 16
#define CK 512

__global__ __launch_bounds__(256)
void attn_kernel(const __hip_bfloat16* __restrict__ qkv,
                 const float* __restrict__ mask,
                 const float* __restrict__ bias_tab,
                 __hip_bfloat16* __restrict__ o) {
    const int bh = blockIdx.y;
    const int b = bh >> 3;
    const int h = bh & 7;
    const int q0 = blockIdx.x * SQ;
    const int t = threadIdx.x;

    __shared__ float qs[SQ][HDIM];
    __shared__ float sc[SQ][CK];
    __shared__ float oacc[SQ][HDIM];
    __shared__ float ms[SQ], ls[SQ], alphas[SQ];

    for (int i = t; i < SQ * HDIM; i += 256) {
        int r = i >> 6, d = i & 63;
        qs[r][d] = 0.125f * __bfloat162float(
            qkv[(size_t)((q0 + r) * BATCH + b) * (3 * DMODEL) + h * HDIM + d]);
        oacc[r][d] = 0.f;
    }
    if (t < SQ) { ms[t] = -1e30f; ls[t] = 0.f; }
    __syncthreads();

    for (int kc = 0; kc < S_LEN; kc += CK) {
        // ---- scores for this chunk ----
        for (int kk = t; kk < CK; kk += 256) {
            int k = kc + kk;
            const __hip_bfloat16* Kp =
                qkv + (size_t)(k * BATCH + b) * (3 * DMODEL) + DMODEL + h * HDIM;
            float srow[SQ];
#pragma unroll
            for (int r = 0; r < SQ; ++r) srow[r] = 0.f;
            for (int dc = 0; dc < HDIM; dc += 16) {
                float kr[16];
#pragma unroll
                for (int dd = 0; dd < 16; ++dd)
                    kr[dd] = __bfloat162float(Kp[dc + dd]);
#pragma unroll
                for (int r = 0; r < SQ; ++r) {
                    float a = srow[r];
#pragma unroll
                    for (int dd = 0; dd < 16; ++dd) a += qs[r][dc + dd] * kr[dd];
                    srow[r] = a;
                }
            }
            int relidx = k - q0 + (S_LEN - 1);
#pragma unroll
            for (int r = 0; r < SQ; ++r) {
                sc[r][kk] = srow[r] + bias_tab[(relidx - r) * NHEAD + h] +
                            mask[(size_t)(q0 + r) * S_LEN + k];
            }
        }
        __syncthreads();

        // ---- online softmax update (16 teams of 16 lanes) ----
        {
            int r = t >> 4, j = t & 15;
            float mx = -1e30f;
            for (int kk = j; kk < CK; kk += 16) mx = fmaxf(mx, sc[r][kk]);
#pragma unroll
            for (int off = 8; off; off >>= 1) mx = fmaxf(mx, __shfl_xor(mx, off));
            float mold = ms[r];
            float mnew = fmaxf(mold, mx);
            float sum = 0.f;
            for (int kk = j; kk < CK; kk += 16) {
                float e = __expf(sc[r][kk] - mnew);
                sc[r][kk] = e;
                sum += e;
            }
#pragma unroll
            for (int off = 8; off; off >>= 1) sum += __shfl_xor(sum, off);
            if (j == 0) {
                float alpha = __expf(mold - mnew);
                alphas[r] = alpha;
                ls[r] = ls[r] * alpha + sum;
                ms[r] = mnew;
            }
        }
        __syncthreads();

        // ---- O accumulation: d = t&63, rows 4*(t>>6) .. +3 ----
        {
            int d = t & 63, g = t >> 6;
            float a0 = 0, a1 = 0, a2 = 0, a3 = 0;
            const __hip_bfloat16* Vp =
                qkv + (size_t)(kc * BATCH + b) * (3 * DMODEL) + 2 * DMODEL + h * HDIM + d;
            for (int kk = 0; kk < CK; ++kk) {
                float vv = __bfloat162float(Vp[(size_t)kk * BATCH * 3 * DMODEL]);
                a0 += sc[g * 4 + 0][kk] * vv;
                a1 += sc[g * 4 + 1][kk] * vv;
                a2 += sc[g * 4 + 2][kk] * vv;
                a3 += sc[g * 4 + 3][kk] * vv;
            }
            oacc[g * 4 + 0][d] = oacc[g * 4 + 0][d] * alphas[g * 4 + 0] + a0;
            oacc[g * 4 + 1][d] = oacc[g * 4 + 1][d] * alphas[g * 4 + 1] + a1;
            oacc[g * 4 + 2][d] = oacc[g * 4 + 2][d] * alphas[g * 4 + 2] + a2;
            oacc[g * 4 + 3][d] = oacc[g * 4 + 3][d] * alphas[g * 4 + 3] + a3;
        }
        __syncthreads();
    }

    for (int i = t; i < SQ * HDIM; i += 256) {
        int r = i >> 6, d = i & 63;
        float v = oacc[r][d] / ls[r];
        o[(size_t)((q0 + r) * BATCH + b) * DMODEL + h * HDIM + d] = __float2bfloat16(v);
    }
}

// ---------------------------------------------------------------------------
// Fused residual + LayerNorm: t = resid + gin; out = LN(t)*w + b.
// Writes f32 always; optionally bf16 copy (for downstream GEMM A-operand).
// One wave per row of 512.
// ---------------------------------------------------------------------------
__global__ __launch_bounds__(64)
void ln_kernel(const float* __restrict__ resid,
               const float* __restrict__ gin,
               const float* __restrict__ w,
               const float* __restrict__ b,
               float* __restrict__ outf,
               __hip_bfloat16* __restrict__ outb) {
    const int row = blockIdx.x;
    const int lane = threadIdx.x;
    const float* rp = resid + (size_t)row * DMODEL;
    const float* gp = gin + (size_t)row * DMODEL;

    float v[8];
    float s = 0.f, s2 = 0.f;
#pragma unroll
    for (int i = 0; i < 8; ++i) {
        int d = i * 64 + lane;
        float x = rp[d] + gp[d];
        v[i] = x;
        s += x;
        s2 += x * x;
    }
#pragma unroll
    for (int off = 32; off; off >>= 1) {
        s  += __shfl_xor(s, off);
        s2 += __shfl_xor(s2, off);
    }
    float mu = s * (1.f / DMODEL);
    float var = s2 * (1.f / DMODEL) - mu * mu;
    float rs = rsqrtf(var + 1e-5f);
#pragma unroll
    for (int i = 0; i < 8; ++i) {
        int d = i * 64 + lane;
        float y = (v[i] - mu) * rs * w[d] + b[d];
        outf[(size_t)row * DMODEL + d] = y;
        if (outb) outb[(size_t)row * DMODEL + d] = __float2bfloat16(y);
    }
}

// ---------------------------------------------------------------------------
extern "C" void kernel_launch(void* const* d_in, const int* in_sizes, int n_in,
                              void* d_out, int out_size, void* d_ws, size_t ws_size,
                              hipStream_t stream) {
    const float* x          = (const float*)d_in[0];
    const float* attn_mask  = (const float*)d_in[1];
    const float* in_proj_w  = (const float*)d_in[2];
    const float* in_proj_b  = (const float*)d_in[3];
    const float* out_proj_w = (const float*)d_in[4];
    const float* out_proj_b = (const float*)d_in[5];
    const float* lin1_w     = (const float*)d_in[6];
    const float* lin1_b     = (const float*)d_in[7];
    const float* lin2_w     = (const float*)d_in[8];
    const float* lin2_b     = (const float*)d_in[9];
    const float* ln1_w      = (const float*)d_in[10];
    const float* ln1_b      = (const float*)d_in[11];
    const float* ln2_w      = (const float*)d_in[12];
    const float* ln2_b      = (const float*)d_in[13];
    const float* rel_emb    = (const float*)d_in[14];

    char* ws = (char*)d_ws;
    size_t off = 0;
    auto alloc = [&](size_t bytes) {
        char* p = ws + off;
        off += (bytes + 255) / 256 * 256;
        return (void*)p;
    };
    float* bias_tab       = (float*)alloc((2 * S_LEN - 1) * NHEAD * 4);
    __hip_bfloat16* wqkvb = (__hip_bfloat16*)alloc((size_t)3 * DMODEL * DMODEL * 2);
    __hip_bfloat16* wob   = (__hip_bfloat16*)alloc((size_t)DMODEL * DMODEL * 2);
    __hip_bfloat16* w1b   = (__hip_bfloat16*)alloc((size_t)DFF * DMODEL * 2);
    __hip_bfloat16* w2b   = (__hip_bfloat16*)alloc((size_t)DMODEL * DFF * 2);
    __hip_bfloat16* qkv   = (__hip_bfloat16*)alloc((size_t)NROWS * 3 * DMODEL * 2);
    __hip_bfloat16* o     = (__hip_bfloat16*)alloc((size_t)NROWS * DMODEL * 2);
    float* tmp            = (float*)alloc((size_t)NROWS * DMODEL * 4);
    float* yf             = (float*)alloc((size_t)NROWS * DMODEL * 4);
    __hip_bfloat16* yb    = (__hip_bfloat16*)alloc((size_t)NROWS * DMODEL * 2);
    __hip_bfloat16* ffb   = (__hip_bfloat16*)alloc((size_t)NROWS * DFF * 2);
    // total ~115 MB

    float* out = (float*)d_out;

    // 0. weight casts + bias table
    cast_kernel<<<dim3(3 * DMODEL * DMODEL / 1024), 256, 0, stream>>>(in_proj_w, wqkvb, 3 * DMODEL * DMODEL);
    cast_kernel<<<dim3(DMODEL * DMODEL / 1024), 256, 0, stream>>>(out_proj_w, wob, DMODEL * DMODEL);
    cast_kernel<<<dim3(DFF * DMODEL / 1024), 256, 0, stream>>>(lin1_w, w1b, DFF * DMODEL);
    cast_kernel<<<dim3(DMODEL * DFF / 1024), 256, 0, stream>>>(lin2_w, w2b, DMODEL * DFF);
    bias_table_kernel<<<dim3(8), 256, 0, stream>>>(rel_emb, bias_tab);

    // 1. qkv = x @ in_proj_w^T + in_proj_b           [8192][1536] bf16
    gemm_nt<true, false, true><<<dim3(24, 128), 256, 0, stream>>>(
        x, wqkvb, in_proj_b, qkv, NROWS, 3 * DMODEL, DMODEL);

    // 2. attention -> o                              [8192][512] bf16
    attn_kernel<<<dim3(S_LEN / SQ, BATCH * NHEAD), 256, 0, stream>>>(
        qkv, attn_mask, bias_tab, o);

    // 3. tmp = o @ out_proj_w^T + out_proj_b         [8192][512] f32
    gemm_nt<false, false, false><<<dim3(8, 128), 256, 0, stream>>>(
        o, wob, out_proj_b, tmp, NROWS, DMODEL, DMODEL);

    // 4. y = LN(x + tmp)  (f32 + bf16 copies)
    ln_kernel<<<dim3(NROWS), 64, 0, stream>>>(x, tmp, ln1_w, ln1_b, yf, yb);

    // 5. ff = relu(y @ lin1_w^T + lin1_b)            [8192][2048] bf16
    gemm_nt<false, true, true><<<dim3(32, 128), 256, 0, stream>>>(
        yb, w1b, lin1_b, ffb, NROWS, DFF, DMODEL);

    // 6. tmp = ff @ lin2_w^T + lin2_b                [8192][512] f32
    gemm_nt<false, false, false><<<dim3(8, 128), 256, 0, stream>>>(
        ffb, w2b, lin2_b, tmp, NROWS, DMODEL, DFF);

    // 7. out = LN(y + tmp)                           [8192][512] f32
    ln_kernel<<<dim3(NROWS), 64, 0, stream>>>(yf, tmp, ln2_w, ln2_b, out, nullptr);
}

// Round 3
// 709.368 us; speedup vs baseline: 1.8979x; 1.8979x over previous
//
#include <hip/hip_runtime.h>
#include <hip/hip_bf16.h>

// ---------------------------------------------------------------------------
// Transformer encoder layer (post-norm) on MI355X. f32 in/out, bf16 MFMA core.
// S=1024 B=8 D=512 H=8 HD=64 DFF=2048, N = S*B = 8192 rows.
// Round 2: MFMA flash attention (QK^T and PV on matrix cores).
// ---------------------------------------------------------------------------

#define S_LEN 1024
#define BATCH 8
#define DMODEL 512
#define NHEAD 8
#define HDIM 64
#define DFF 2048
#define NROWS (S_LEN * BATCH)   // 8192

typedef __bf16 bf16x8 __attribute__((ext_vector_type(8)));
typedef float f32x4 __attribute__((ext_vector_type(4)));

// XOR-swizzled LDS addressing (granularity 8 elems = 16B) — keeps b128 reads
// aligned+conflict-free while spreading transpose writes across banks.
__device__ __forceinline__ int vt_addr(int d, int k) {
    return d * 64 + ((((k >> 3) ^ (d & 7))) << 3) + (k & 7);
}
__device__ __forceinline__ int p_addr(int r, int k) {
    return r * 64 + ((((k >> 3) ^ (r & 7))) << 3) + (k & 7);
}

// ---------------------------------------------------------------------------
__global__ __launch_bounds__(256)
void cast_kernel(const float* __restrict__ in, __hip_bfloat16* __restrict__ out, int n) {
    int i = (blockIdx.x * blockDim.x + threadIdx.x) * 4;
    if (i + 3 < n) {
        float4 v = *(const float4*)(in + i);
        out[i + 0] = __float2bfloat16(v.x);
        out[i + 1] = __float2bfloat16(v.y);
        out[i + 2] = __float2bfloat16(v.z);
        out[i + 3] = __float2bfloat16(v.w);
    }
}

// ---------------------------------------------------------------------------
// bias_tab[rel + 1023][h], rel = k - q. Exact integer bucket thresholds.
// ---------------------------------------------------------------------------
__global__ void bias_table_kernel(const float* __restrict__ rel_emb,
                                  float* __restrict__ bias_tab) {
    int idx = blockIdx.x * blockDim.x + threadIdx.x;
    if (idx >= 2 * S_LEN - 1) return;
    int rel = idx - (S_LEN - 1);
    int bucket = (rel > 0) ? 16 : 0;
    int rp = rel < 0 ? -rel : rel;
    int v;
    if (rp < 8)          v = rp;
    else if (rp < 12)    v = 8;
    else if (rp < 16)    v = 9;
    else if (rp < 23)    v = 10;
    else if (rp < 32)    v = 11;
    else if (rp < 46)    v = 12;
    else if (rp < 64)    v = 13;
    else if (rp < 91)    v = 14;
    else                 v = 15;
    bucket += v;
    for (int h = 0; h < NHEAD; ++h)
        bias_tab[idx * NHEAD + h] = rel_emb[bucket * NHEAD + h];
}

// ---------------------------------------------------------------------------
// NT GEMM: Y[n][m] = sum_k A[n][k] * W[m][k] + bias[m]
// MODE: 0 = f32 row-major out, 1 = bf16 row-major out,
//       2 = qkv scatter: out[sect][b*8+h][s][d] bf16  (sect=col>>9 per block)
// ---------------------------------------------------------------------------
template <bool A_F32, bool RELU, int MODE>
__global__ __launch_bounds__(256)
void gemm_nt(const void* __restrict__ Av,
             const __hip_bfloat16* __restrict__ W,
             const float* __restrict__ bias,
             void* __restrict__ outv,
             int N, int M, int K) {
    const int wave = threadIdx.x >> 6;
    const int lane = threadIdx.x & 63;
    const int m16  = lane & 15;
    const int quad = lane >> 4;
    const int row0 = blockIdx.y * 64 + wave * 16;
    const int col0 = blockIdx.x * 64;

    const __bf16* Wp = (const __bf16*)W + (size_t)(col0 + m16) * K + quad * 8;
    const size_t wstride = (size_t)16 * K;

    f32x4 acc[4] = {f32x4{0,0,0,0}, f32x4{0,0,0,0}, f32x4{0,0,0,0}, f32x4{0,0,0,0}};

    if (A_F32) {
        const float* Ap = (const float*)Av + (size_t)(row0 + m16) * K + quad * 8;
        for (int k0 = 0; k0 < K; k0 += 32) {
            float4 lo = *(const float4*)(Ap + k0);
            float4 hi = *(const float4*)(Ap + k0 + 4);
            union { bf16x8 v; __hip_bfloat16 e[8]; } u;
            u.e[0] = __float2bfloat16(lo.x); u.e[1] = __float2bfloat16(lo.y);
            u.e[2] = __float2bfloat16(lo.z); u.e[3] = __float2bfloat16(lo.w);
            u.e[4] = __float2bfloat16(hi.x); u.e[5] = __float2bfloat16(hi.y);
            u.e[6] = __float2bfloat16(hi.z); u.e[7] = __float2bfloat16(hi.w);
#pragma unroll
            for (int c = 0; c < 4; ++c) {
                bf16x8 bfr = *(const bf16x8*)(Wp + c * wstride + k0);
                acc[c] = __builtin_amdgcn_mfma_f32_16x16x32_bf16(u.v, bfr, acc[c], 0, 0, 0);
            }
        }
    } else {
        const __bf16* Ap = (const __bf16*)Av + (size_t)(row0 + m16) * K + quad * 8;
        for (int k0 = 0; k0 < K; k0 += 32) {
            bf16x8 a = *(const bf16x8*)(Ap + k0);
#pragma unroll
            for (int c = 0; c < 4; ++c) {
                bf16x8 bfr = *(const bf16x8*)(Wp + c * wstride + k0);
                acc[c] = __builtin_amdgcn_mfma_f32_16x16x32_bf16(a, bfr, acc[c], 0, 0, 0);
            }
        }
    }

    if (MODE == 2) {
        const int sect = col0 >> 9;          // 0=q 1=k 2=v (block-uniform)
        const int h = (col0 >> 6) & 7;
        __hip_bfloat16* qkvb = (__hip_bfloat16*)outv;
#pragma unroll
        for (int c = 0; c < 4; ++c) {
            int d = c * 16 + m16;
            float bv = bias[col0 + c * 16 + m16];
#pragma unroll
            for (int r = 0; r < 4; ++r) {
                int row = row0 + quad * 4 + r;
                int s = row >> 3, bb = row & 7;
                float v = acc[c][r] + bv;
                size_t idx = (((size_t)(sect * 64 + bb * 8 + h)) * S_LEN + s) * HDIM + d;
                qkvb[idx] = __float2bfloat16(v);
            }
        }
    } else {
#pragma unroll
        for (int c = 0; c < 4; ++c) {
            int col = col0 + c * 16 + m16;
            float bv = bias[col];
#pragma unroll
            for (int r = 0; r < 4; ++r) {
                int row = row0 + quad * 4 + r;
                float v = acc[c][r] + bv;
                if (RELU) v = fmaxf(v, 0.f);
                if (MODE == 1) ((__hip_bfloat16*)outv)[(size_t)row * M + col] = __float2bfloat16(v);
                else           ((float*)outv)[(size_t)row * M + col] = v;
            }
        }
    }
}

// ---------------------------------------------------------------------------
// MFMA flash attention.
// Grid (16 q-tiles, 64 bh); block 256 = 4 waves; wave w owns q rows w*16..+15.
// Q/K/V: [sect][bh][S][HD] bf16, contiguous per (b,h).
// Per 64-key chunk: QK^T (8 MFMA), bias(LDS)+mask(global), online softmax,
// P->LDS (swizzled) -> A-frag, PV (8 MFMA) vs LDS-staged V^T (swizzled).
// Output written bf16 at o[(s*8+b)][h*64+d] for the out_proj GEMM.
// ---------------------------------------------------------------------------
__global__ __launch_bounds__(256, 4)
void attn_mfma(const __hip_bfloat16* __restrict__ qkv_bhsd,
               const float* __restrict__ mask,
               const float* __restrict__ bias_tab,
               __hip_bfloat16* __restrict__ o) {
    const int bh = blockIdx.y;
    const int b = bh >> 3, h = bh & 7;
    const int q0 = blockIdx.x * 64;
    const int t = threadIdx.x;
    const int w = t >> 6, lane = t & 63, m16 = lane & 15, quad = lane >> 4;

    const __bf16* Qb = (const __bf16*)qkv_bhsd + (size_t)bh * (S_LEN * HDIM);
    const __bf16* Kb = (const __bf16*)qkv_bhsd + (size_t)(64 + bh) * (S_LEN * HDIM);
    const __bf16* Vb = (const __bf16*)qkv_bhsd + (size_t)(128 + bh) * (S_LEN * HDIM);

    __shared__ __bf16 VT[64 * 64];       // V^T tile, swizzled
    __shared__ __bf16 P[4][16 * 64];     // per-wave P tile, swizzled
    __shared__ float bias_l[1088];       // bias for rel = k - q, this block

    // bias_l[j] = bias(rel = j - 63 - q0 ... ) : j = k - (q-q0) + 63, j in [0,1086]
    for (int i = t; i < 1087; i += 256)
        bias_l[i] = bias_tab[(i + 960 - q0) * NHEAD + h];

    // Q fragments for the whole K loop, scaled by exact 1/8
    bf16x8 aQ0, aQ1;
    {
        const __bf16* qp = Qb + (size_t)(q0 + w * 16 + m16) * HDIM + quad * 8;
        bf16x8 t0 = *(const bf16x8*)qp;
        bf16x8 t1 = *(const bf16x8*)(qp + 32);
#pragma unroll
        for (int j = 0; j < 8; ++j) {
            t0[j] = (__bf16)((float)t0[j] * 0.125f);
            t1[j] = (__bf16)((float)t1[j] * 0.125f);
        }
        aQ0 = t0; aQ1 = t1;
    }

    f32x4 accO[4] = {f32x4{0,0,0,0}, f32x4{0,0,0,0}, f32x4{0,0,0,0}, f32x4{0,0,0,0}};
    float mrow[4] = {-1e30f, -1e30f, -1e30f, -1e30f};
    float lrow[4] = {0.f, 0.f, 0.f, 0.f};

    for (int kc = 0; kc < S_LEN; kc += 64) {
        __syncthreads();   // protect VT from previous iteration's readers
        // ---- stage V^T (transpose via swizzled LDS) ----
#pragma unroll
        for (int it = 0; it < 2; ++it) {
            int kv = it * 32 + (t >> 3);
            int d0 = (t & 7) * 8;
            bf16x8 vv = *(const bf16x8*)(Vb + (size_t)(kc + kv) * HDIM + d0);
#pragma unroll
            for (int j = 0; j < 8; ++j)
                VT[vt_addr(d0 + j, kv)] = vv[j];
        }
        __syncthreads();

        // ---- QK^T ----
        f32x4 accS[4] = {f32x4{0,0,0,0}, f32x4{0,0,0,0}, f32x4{0,0,0,0}, f32x4{0,0,0,0}};
        {
            const __bf16* kp = Kb + (size_t)(kc + m16) * HDIM + quad * 8;
#pragma unroll
            for (int c = 0; c < 4; ++c) {
                bf16x8 b0 = *(const bf16x8*)(kp + (size_t)c * 16 * HDIM);
                bf16x8 b1 = *(const bf16x8*)(kp + (size_t)c * 16 * HDIM + 32);
                accS[c] = __builtin_amdgcn_mfma_f32_16x16x32_bf16(aQ0, b0, accS[c], 0, 0, 0);
                accS[c] = __builtin_amdgcn_mfma_f32_16x16x32_bf16(aQ1, b1, accS[c], 0, 0, 0);
            }
        }

        // ---- bias + mask ----
        float sc[4][4];
#pragma unroll
        for (int c = 0; c < 4; ++c) {
            int kcol = kc + c * 16 + m16;
#pragma unroll
            for (int r = 0; r < 4; ++r) {
                int row = w * 16 + quad * 4 + r;
                sc[c][r] = accS[c][r] + bias_l[kcol - row + 63]
                         + mask[(size_t)(q0 + row) * S_LEN + kcol];
            }
        }

        // ---- online softmax (row state replicated across 16-lane groups) ----
        float alpha[4];
#pragma unroll
        for (int r = 0; r < 4; ++r) {
            float mx = fmaxf(fmaxf(sc[0][r], sc[1][r]), fmaxf(sc[2][r], sc[3][r]));
#pragma unroll
            for (int off = 1; off < 16; off <<= 1) mx = fmaxf(mx, __shfl_xor(mx, off));
            float mnew = fmaxf(mrow[r], mx);
            alpha[r] = __expf(mrow[r] - mnew);
            float s = 0.f;
#pragma unroll
            for (int c = 0; c < 4; ++c) {
                float e = __expf(sc[c][r] - mnew);
                sc[c][r] = e;
                s += e;
            }
#pragma unroll
            for (int off = 1; off < 16; off <<= 1) s += __shfl_xor(s, off);
            lrow[r] = lrow[r] * alpha[r] + s;
            mrow[r] = mnew;
        }

        // ---- P -> LDS (C-layout -> A-layout round trip) ----
#pragma unroll
        for (int c = 0; c < 4; ++c)
#pragma unroll
            for (int r = 0; r < 4; ++r)
                P[w][p_addr(quad * 4 + r, c * 16 + m16)] = (__bf16)sc[c][r];

        // ---- rescale O ----
#pragma unroll
        for (int c = 0; c < 4; ++c)
#pragma unroll
            for (int r = 0; r < 4; ++r) accO[c][r] *= alpha[r];

        // ---- PV ----
        bf16x8 aP0 = *(const bf16x8*)&P[w][p_addr(m16, quad * 8)];
        bf16x8 aP1 = *(const bf16x8*)&P[w][p_addr(m16, 32 + quad * 8)];
#pragma unroll
        for (int c = 0; c < 4; ++c) {
            bf16x8 v0 = *(const bf16x8*)&VT[vt_addr(c * 16 + m16, quad * 8)];
            bf16x8 v1 = *(const bf16x8*)&VT[vt_addr(c * 16 + m16, 32 + quad * 8)];
            accO[c] = __builtin_amdgcn_mfma_f32_16x16x32_bf16(aP0, v0, accO[c], 0, 0, 0);
            accO[c] = __builtin_amdgcn_mfma_f32_16x16x32_bf16(aP1, v1, accO[c], 0, 0, 0);
        }
    }

    // ---- epilogue: normalize, write o[(s*8+b)][h*64+d] bf16 ----
#pragma unroll
    for (int c = 0; c < 4; ++c)
#pragma unroll
        for (int r = 0; r < 4; ++r) {
            int row = q0 + w * 16 + quad * 4 + r;
            int d = c * 16 + m16;
            float v = accO[c][r] / lrow[r];
            o[((size_t)row * BATCH + b) * DMODEL + h * HDIM + d] = __float2bfloat16(v);
        }
}

// ---------------------------------------------------------------------------
// Fused residual + LayerNorm. One wave per row of 512.
// ---------------------------------------------------------------------------
__global__ __launch_bounds__(64)
void ln_kernel(const float* __restrict__ resid,
               const float* __restrict__ gin,
               const float* __restrict__ w,
               const float* __restrict__ b,
               float* __restrict__ outf,
               __hip_bfloat16* __restrict__ outb) {
    const int row = blockIdx.x;
    const int lane = threadIdx.x;
    const float* rp = resid + (size_t)row * DMODEL;
    const float* gp = gin + (size_t)row * DMODEL;

    float v[8];
    float s = 0.f, s2 = 0.f;
#pragma unroll
    for (int i = 0; i < 8; ++i) {
        int d = i * 64 + lane;
        float x = rp[d] + gp[d];
        v[i] = x;
        s += x;
        s2 += x * x;
    }
#pragma unroll
    for (int off = 32; off; off >>= 1) {
        s  += __shfl_xor(s, off);
        s2 += __shfl_xor(s2, off);
    }
    float mu = s * (1.f / DMODEL);
    float var = s2 * (1.f / DMODEL) - mu * mu;
    float rs = rsqrtf(var + 1e-5f);
#pragma unroll
    for (int i = 0; i < 8; ++i) {
        int d = i * 64 + lane;
        float y = (v[i] - mu) * rs * w[d] + b[d];
        outf[(size_t)row * DMODEL + d] = y;
        if (outb) outb[(size_t)row * DMODEL + d] = __float2bfloat16(y);
    }
}

// ---------------------------------------------------------------------------
extern "C" void kernel_launch(void* const* d_in, const int* in_sizes, int n_in,
                              void* d_out, int out_size, void* d_ws, size_t ws_size,
                              hipStream_t stream) {
    const float* x          = (const float*)d_in[0];
    const float* attn_mask  = (const float*)d_in[1];
    const float* in_proj_w  = (const float*)d_in[2];
    const float* in_proj_b  = (const float*)d_in[3];
    const float* out_proj_w = (const float*)d_in[4];
    const float* out_proj_b = (const float*)d_in[5];
    const float* lin1_w     = (const float*)d_in[6];
    const float* lin1_b     = (const float*)d_in[7];
    const float* lin2_w     = (const float*)d_in[8];
    const float* lin2_b     = (const float*)d_in[9];
    const float* ln1_w      = (const float*)d_in[10];
    const float* ln1_b      = (const float*)d_in[11];
    const float* ln2_w      = (const float*)d_in[12];
    const float* ln2_b      = (const float*)d_in[13];
    const float* rel_emb    = (const float*)d_in[14];

    char* ws = (char*)d_ws;
    size_t off = 0;
    auto alloc = [&](size_t bytes) {
        char* p = ws + off;
        off += (bytes + 255) / 256 * 256;
        return (void*)p;
    };
    float* bias_tab       = (float*)alloc((2 * S_LEN - 1) * NHEAD * 4);
    __hip_bfloat16* wqkvb = (__hip_bfloat16*)alloc((size_t)3 * DMODEL * DMODEL * 2);
    __hip_bfloat16* wob   = (__hip_bfloat16*)alloc((size_t)DMODEL * DMODEL * 2);
    __hip_bfloat16* w1b   = (__hip_bfloat16*)alloc((size_t)DFF * DMODEL * 2);
    __hip_bfloat16* w2b   = (__hip_bfloat16*)alloc((size_t)DMODEL * DFF * 2);
    __hip_bfloat16* qkvb  = (__hip_bfloat16*)alloc((size_t)3 * 64 * S_LEN * HDIM * 2);
    __hip_bfloat16* o     = (__hip_bfloat16*)alloc((size_t)NROWS * DMODEL * 2);
    float* tmp            = (float*)alloc((size_t)NROWS * DMODEL * 4);
    float* yf             = (float*)alloc((size_t)NROWS * DMODEL * 4);
    __hip_bfloat16* yb    = (__hip_bfloat16*)alloc((size_t)NROWS * DMODEL * 2);
    __hip_bfloat16* ffb   = (__hip_bfloat16*)alloc((size_t)NROWS * DFF * 2);

    float* out = (float*)d_out;

    // 0. weight casts + bias table
    cast_kernel<<<dim3(3 * DMODEL * DMODEL / 1024), 256, 0, stream>>>(in_proj_w, wqkvb, 3 * DMODEL * DMODEL);
    cast_kernel<<<dim3(DMODEL * DMODEL / 1024), 256, 0, stream>>>(out_proj_w, wob, DMODEL * DMODEL);
    cast_kernel<<<dim3(DFF * DMODEL / 1024), 256, 0, stream>>>(lin1_w, w1b, DFF * DMODEL);
    cast_kernel<<<dim3(DMODEL * DFF / 1024), 256, 0, stream>>>(lin2_w, w2b, DMODEL * DFF);
    bias_table_kernel<<<dim3(8), 256, 0, stream>>>(rel_emb, bias_tab);

    // 1. qkv projection, scattered into [sect][bh][s][d] bf16
    gemm_nt<true, false, 2><<<dim3(24, 128), 256, 0, stream>>>(
        x, wqkvb, in_proj_b, qkvb, NROWS, 3 * DMODEL, DMODEL);

    // 2. MFMA flash attention -> o [(s*8+b)][512] bf16
    attn_mfma<<<dim3(S_LEN / 64, BATCH * NHEAD), 256, 0, stream>>>(
        qkvb, attn_mask, bias_tab, o);

    // 3. tmp = o @ out_proj_w^T + out_proj_b         f32
    gemm_nt<false, false, 0><<<dim3(8, 128), 256, 0, stream>>>(
        o, wob, out_proj_b, tmp, NROWS, DMODEL, DMODEL);

    // 4. y = LN(x + tmp)
    ln_kernel<<<dim3(NROWS), 64, 0, stream>>>(x, tmp, ln1_w, ln1_b, yf, yb);

    // 5. ff = relu(y @ lin1_w^T + lin1_b)            bf16
    gemm_nt<false, true, 1><<<dim3(32, 128), 256, 0, stream>>>(
        yb, w1b, lin1_b, ffb, NROWS, DFF, DMODEL);

    // 6. tmp = ff @ lin2_w^T + lin2_b                f32
    gemm_nt<false, false, 0><<<dim3(8, 128), 256, 0, stream>>>(
        ffb, w2b, lin2_b, tmp, NROWS, DMODEL, DFF);

    // 7. out = LN(y + tmp)                           f32
    ln_kernel<<<dim3(NROWS), 64, 0, stream>>>(yf, tmp, ln2_w, ln2_b, out, nullptr);
}

// Round 4
// 341.024 us; speedup vs baseline: 3.9478x; 2.0801x over previous
//
#include <hip/hip_runtime.h>
#include <hip/hip_bf16.h>

// ---------------------------------------------------------------------------
// Transformer encoder layer (post-norm) on MI355X. f32 in/out, bf16 MFMA core.
// S=1024 B=8 D=512 H=8 HD=64 DFF=2048, N = S*B = 8192 rows.
// Round 3: m97-style LDS-staged GEMM (global_load_lds width=16, swizzled LDS).
// ---------------------------------------------------------------------------

#define S_LEN 1024
#define BATCH 8
#define DMODEL 512
#define NHEAD 8
#define HDIM 64
#define DFF 2048
#define NROWS (S_LEN * BATCH)   // 8192

typedef __bf16 bf16x8 __attribute__((ext_vector_type(8)));
typedef float f32x4 __attribute__((ext_vector_type(4)));

// async global->LDS, 16 B per lane. LDS dest is wave-uniform base + lane*16.
__device__ __forceinline__ void gload16(const void* g, void* l) {
    __builtin_amdgcn_global_load_lds(
        (const __attribute__((address_space(1))) void*)g,
        (__attribute__((address_space(3))) void*)l, 16, 0, 0);
}

// ---------------------------------------------------------------------------
__global__ __launch_bounds__(256)
void cast_kernel(const float* __restrict__ in, __hip_bfloat16* __restrict__ out, int n) {
    int i = (blockIdx.x * blockDim.x + threadIdx.x) * 4;
    if (i + 3 < n) {
        float4 v = *(const float4*)(in + i);
        out[i + 0] = __float2bfloat16(v.x);
        out[i + 1] = __float2bfloat16(v.y);
        out[i + 2] = __float2bfloat16(v.z);
        out[i + 3] = __float2bfloat16(v.w);
    }
}

// ---------------------------------------------------------------------------
// bias_tab[rel + 1023][h], rel = k - q. Exact integer bucket thresholds.
// ---------------------------------------------------------------------------
__global__ void bias_table_kernel(const float* __restrict__ rel_emb,
                                  float* __restrict__ bias_tab) {
    int idx = blockIdx.x * blockDim.x + threadIdx.x;
    if (idx >= 2 * S_LEN - 1) return;
    int rel = idx - (S_LEN - 1);
    int bucket = (rel > 0) ? 16 : 0;
    int rp = rel < 0 ? -rel : rel;
    int v;
    if (rp < 8)          v = rp;
    else if (rp < 12)    v = 8;
    else if (rp < 16)    v = 9;
    else if (rp < 23)    v = 10;
    else if (rp < 32)    v = 11;
    else if (rp < 46)    v = 12;
    else if (rp < 64)    v = 13;
    else if (rp < 91)    v = 14;
    else                 v = 15;
    bucket += v;
    for (int h = 0; h < NHEAD; ++h)
        bias_tab[idx * NHEAD + h] = rel_emb[bucket * NHEAD + h];
}

// ---------------------------------------------------------------------------
// LDS-staged NT GEMM: Y[n][m] = sum_k A[n][k]*W[m][k] + bias[m]
// A:[N][K] bf16, W:[M][K] bf16. Block 256 thr, tile 128 x NTILE, BK=64.
// Staging: global_load_lds 16B/lane; k-block XOR-swizzled by (row&7) in the
// SOURCE address so ds_read_b128 fragment reads are 2-way/bank (free).
// NTILE=128: wave w = quadrant (rows (w>>1)*64, cols (w&1)*64), acc 4x4.
// NTILE=64 : wave w = rows w*32, all 64 cols, acc 4x2.
// MODE: 0 f32 out, 1 bf16 out, 2 qkv scatter out[sect][b*8+h][s][d] bf16.
// ---------------------------------------------------------------------------
template <int MODE, bool RELU, int NTILE>
__global__ __launch_bounds__(256)
void gemm_tile(const __hip_bfloat16* __restrict__ Ab,
               const __hip_bfloat16* __restrict__ Wb,
               const float* __restrict__ bias,
               void* __restrict__ outv,
               int N, int M, int K) {
    constexpr int RT = (NTILE == 128) ? 4 : 2;     // row-tiles per wave
    constexpr int NB = NTILE / 32;                 // B staging groups per wave
    const int w = threadIdx.x >> 6;
    const int lane = threadIdx.x & 63;
    const int m16 = lane & 15;
    const int quad = lane >> 4;
    const int row0 = blockIdx.y * 128;
    const int col0 = blockIdx.x * NTILE;
    const int rowbase = (NTILE == 128) ? (w >> 1) * 64 : w * 32;
    const int colbase = (NTILE == 128) ? (w & 1) * 64 : 0;

    __shared__ __align__(16) __bf16 As[128 * 64];
    __shared__ __align__(16) __bf16 Bs[NTILE * 64];

    const __bf16* Ap = (const __bf16*)Ab;
    const __bf16* Wp = (const __bf16*)Wb;

    // per-lane staging source offsets
    const int a_row_in_grp = lane >> 3;            // 0..7
    const int kb_sw = (lane & 7) ^ (lane >> 3);    // swizzled k-block slot

    f32x4 acc[4][RT];
#pragma unroll
    for (int c = 0; c < 4; ++c)
#pragma unroll
        for (int r = 0; r < RT; ++r) acc[c][r] = f32x4{0, 0, 0, 0};

    for (int k0 = 0; k0 < K; k0 += 64) {
        // ---- stage A (128x64) : wave w -> 8-row groups w*4 .. w*4+3 ----
#pragma unroll
        for (int i = 0; i < 4; ++i) {
            int grp = w * 4 + i;
            int row = grp * 8 + a_row_in_grp;
            gload16(Ap + (size_t)(row0 + row) * K + k0 + kb_sw * 8,
                    (void*)(As + grp * 512));
        }
        // ---- stage B (NTILEx64) ----
#pragma unroll
        for (int i = 0; i < NB; ++i) {
            int grp = w * NB + i;
            int row = grp * 8 + a_row_in_grp;
            gload16(Wp + (size_t)(col0 + row) * K + k0 + kb_sw * 8,
                    (void*)(Bs + grp * 512));
        }
        __syncthreads();

        // ---- compute ----
#pragma unroll
        for (int kk = 0; kk < 2; ++kk) {
            bf16x8 af[RT], bfr[4];
#pragma unroll
            for (int r = 0; r < RT; ++r) {
                int rr = rowbase + r * 16 + m16;
                int slot = (kk * 4 + quad) ^ (m16 & 7);
                af[r] = *(const bf16x8*)(As + rr * 64 + slot * 8);
            }
#pragma unroll
            for (int c = 0; c < 4; ++c) {
                int rr = colbase + c * 16 + m16;
                int slot = (kk * 4 + quad) ^ (m16 & 7);
                bfr[c] = *(const bf16x8*)(Bs + rr * 64 + slot * 8);
            }
#pragma unroll
            for (int c = 0; c < 4; ++c)
#pragma unroll
                for (int r = 0; r < RT; ++r)
                    acc[c][r] = __builtin_amdgcn_mfma_f32_16x16x32_bf16(
                        af[r], bfr[c], acc[c][r], 0, 0, 0);
        }
        __syncthreads();
    }

    // ---- epilogue ----
#pragma unroll
    for (int c = 0; c < 4; ++c) {
        int col = col0 + colbase + c * 16 + m16;
        float bv = bias[col];
#pragma unroll
        for (int r = 0; r < RT; ++r) {
#pragma unroll
            for (int e = 0; e < 4; ++e) {
                int row = row0 + rowbase + r * 16 + quad * 4 + e;
                float v = acc[c][r][e] + bv;
                if (RELU) v = fmaxf(v, 0.f);
                if (MODE == 0) {
                    ((float*)outv)[(size_t)row * M + col] = v;
                } else if (MODE == 1) {
                    ((__hip_bfloat16*)outv)[(size_t)row * M + col] = __float2bfloat16(v);
                } else {
                    int sect = col >> 9, h = (col >> 6) & 7, d = col & 63;
                    int s = row >> 3, bb = row & 7;
                    size_t idx = (((size_t)(sect * 64 + bb * 8 + h)) * S_LEN + s) * HDIM + d;
                    ((__hip_bfloat16*)outv)[idx] = __float2bfloat16(v);
                }
            }
        }
    }
}

// ---------------------------------------------------------------------------
// MFMA flash attention (unchanged from round 2).
// ---------------------------------------------------------------------------
__device__ __forceinline__ int vt_addr(int d, int k) {
    return d * 64 + ((((k >> 3) ^ (d & 7))) << 3) + (k & 7);
}
__device__ __forceinline__ int p_addr(int r, int k) {
    return r * 64 + ((((k >> 3) ^ (r & 7))) << 3) + (k & 7);
}

__global__ __launch_bounds__(256, 4)
void attn_mfma(const __hip_bfloat16* __restrict__ qkv_bhsd,
               const float* __restrict__ mask,
               const float* __restrict__ bias_tab,
               __hip_bfloat16* __restrict__ o) {
    const int bh = blockIdx.y;
    const int b = bh >> 3, h = bh & 7;
    const int q0 = blockIdx.x * 64;
    const int t = threadIdx.x;
    const int w = t >> 6, lane = t & 63, m16 = lane & 15, quad = lane >> 4;

    const __bf16* Qb = (const __bf16*)qkv_bhsd + (size_t)bh * (S_LEN * HDIM);
    const __bf16* Kb = (const __bf16*)qkv_bhsd + (size_t)(64 + bh) * (S_LEN * HDIM);
    const __bf16* Vb = (const __bf16*)qkv_bhsd + (size_t)(128 + bh) * (S_LEN * HDIM);

    __shared__ __bf16 VT[64 * 64];
    __shared__ __bf16 P[4][16 * 64];
    __shared__ float bias_l[1088];

    for (int i = t; i < 1087; i += 256)
        bias_l[i] = bias_tab[(i + 960 - q0) * NHEAD + h];

    bf16x8 aQ0, aQ1;
    {
        const __bf16* qp = Qb + (size_t)(q0 + w * 16 + m16) * HDIM + quad * 8;
        bf16x8 t0 = *(const bf16x8*)qp;
        bf16x8 t1 = *(const bf16x8*)(qp + 32);
#pragma unroll
        for (int j = 0; j < 8; ++j) {
            t0[j] = (__bf16)((float)t0[j] * 0.125f);
            t1[j] = (__bf16)((float)t1[j] * 0.125f);
        }
        aQ0 = t0; aQ1 = t1;
    }

    f32x4 accO[4] = {f32x4{0,0,0,0}, f32x4{0,0,0,0}, f32x4{0,0,0,0}, f32x4{0,0,0,0}};
    float mrow[4] = {-1e30f, -1e30f, -1e30f, -1e30f};
    float lrow[4] = {0.f, 0.f, 0.f, 0.f};

    for (int kc = 0; kc < S_LEN; kc += 64) {
        __syncthreads();
#pragma unroll
        for (int it = 0; it < 2; ++it) {
            int kv = it * 32 + (t >> 3);
            int d0 = (t & 7) * 8;
            bf16x8 vv = *(const bf16x8*)(Vb + (size_t)(kc + kv) * HDIM + d0);
#pragma unroll
            for (int j = 0; j < 8; ++j)
                VT[vt_addr(d0 + j, kv)] = vv[j];
        }
        __syncthreads();

        f32x4 accS[4] = {f32x4{0,0,0,0}, f32x4{0,0,0,0}, f32x4{0,0,0,0}, f32x4{0,0,0,0}};
        {
            const __bf16* kp = Kb + (size_t)(kc + m16) * HDIM + quad * 8;
#pragma unroll
            for (int c = 0; c < 4; ++c) {
                bf16x8 b0 = *(const bf16x8*)(kp + (size_t)c * 16 * HDIM);
                bf16x8 b1 = *(const bf16x8*)(kp + (size_t)c * 16 * HDIM + 32);
                accS[c] = __builtin_amdgcn_mfma_f32_16x16x32_bf16(aQ0, b0, accS[c], 0, 0, 0);
                accS[c] = __builtin_amdgcn_mfma_f32_16x16x32_bf16(aQ1, b1, accS[c], 0, 0, 0);
            }
        }

        float sc[4][4];
#pragma unroll
        for (int c = 0; c < 4; ++c) {
            int kcol = kc + c * 16 + m16;
#pragma unroll
            for (int r = 0; r < 4; ++r) {
                int row = w * 16 + quad * 4 + r;
                sc[c][r] = accS[c][r] + bias_l[kcol - row + 63]
                         + mask[(size_t)(q0 + row) * S_LEN + kcol];
            }
        }

        float alpha[4];
#pragma unroll
        for (int r = 0; r < 4; ++r) {
            float mx = fmaxf(fmaxf(sc[0][r], sc[1][r]), fmaxf(sc[2][r], sc[3][r]));
#pragma unroll
            for (int off = 1; off < 16; off <<= 1) mx = fmaxf(mx, __shfl_xor(mx, off));
            float mnew = fmaxf(mrow[r], mx);
            alpha[r] = __expf(mrow[r] - mnew);
            float s = 0.f;
#pragma unroll
            for (int c = 0; c < 4; ++c) {
                float e = __expf(sc[c][r] - mnew);
                sc[c][r] = e;
                s += e;
            }
#pragma unroll
            for (int off = 1; off < 16; off <<= 1) s += __shfl_xor(s, off);
            lrow[r] = lrow[r] * alpha[r] + s;
            mrow[r] = mnew;
        }

#pragma unroll
        for (int c = 0; c < 4; ++c)
#pragma unroll
            for (int r = 0; r < 4; ++r)
                P[w][p_addr(quad * 4 + r, c * 16 + m16)] = (__bf16)sc[c][r];

#pragma unroll
        for (int c = 0; c < 4; ++c)
#pragma unroll
            for (int r = 0; r < 4; ++r) accO[c][r] *= alpha[r];

        bf16x8 aP0 = *(const bf16x8*)&P[w][p_addr(m16, quad * 8)];
        bf16x8 aP1 = *(const bf16x8*)&P[w][p_addr(m16, 32 + quad * 8)];
#pragma unroll
        for (int c = 0; c < 4; ++c) {
            bf16x8 v0 = *(const bf16x8*)&VT[vt_addr(c * 16 + m16, quad * 8)];
            bf16x8 v1 = *(const bf16x8*)&VT[vt_addr(c * 16 + m16, 32 + quad * 8)];
            accO[c] = __builtin_amdgcn_mfma_f32_16x16x32_bf16(aP0, v0, accO[c], 0, 0, 0);
            accO[c] = __builtin_amdgcn_mfma_f32_16x16x32_bf16(aP1, v1, accO[c], 0, 0, 0);
        }
    }

#pragma unroll
    for (int c = 0; c < 4; ++c)
#pragma unroll
        for (int r = 0; r < 4; ++r) {
            int row = q0 + w * 16 + quad * 4 + r;
            int d = c * 16 + m16;
            float v = accO[c][r] / lrow[r];
            o[((size_t)row * BATCH + b) * DMODEL + h * HDIM + d] = __float2bfloat16(v);
        }
}

// ---------------------------------------------------------------------------
// Fused residual + LayerNorm. One wave per row of 512.
// ---------------------------------------------------------------------------
__global__ __launch_bounds__(64)
void ln_kernel(const float* __restrict__ resid,
               const float* __restrict__ gin,
               const float* __restrict__ w,
               const float* __restrict__ b,
               float* __restrict__ outf,
               __hip_bfloat16* __restrict__ outb) {
    const int row = blockIdx.x;
    const int lane = threadIdx.x;
    const float* rp = resid + (size_t)row * DMODEL;
    const float* gp = gin + (size_t)row * DMODEL;

    float v[8];
    float s = 0.f, s2 = 0.f;
#pragma unroll
    for (int i = 0; i < 8; ++i) {
        int d = i * 64 + lane;
        float x = rp[d] + gp[d];
        v[i] = x;
        s += x;
        s2 += x * x;
    }
#pragma unroll
    for (int off = 32; off; off >>= 1) {
        s  += __shfl_xor(s, off);
        s2 += __shfl_xor(s2, off);
    }
    float mu = s * (1.f / DMODEL);
    float var = s2 * (1.f / DMODEL) - mu * mu;
    float rs = rsqrtf(var + 1e-5f);
#pragma unroll
    for (int i = 0; i < 8; ++i) {
        int d = i * 64 + lane;
        float y = (v[i] - mu) * rs * w[d] + b[d];
        outf[(size_t)row * DMODEL + d] = y;
        if (outb) outb[(size_t)row * DMODEL + d] = __float2bfloat16(y);
    }
}

// ---------------------------------------------------------------------------
extern "C" void kernel_launch(void* const* d_in, const int* in_sizes, int n_in,
                              void* d_out, int out_size, void* d_ws, size_t ws_size,
                              hipStream_t stream) {
    const float* x          = (const float*)d_in[0];
    const float* attn_mask  = (const float*)d_in[1];
    const float* in_proj_w  = (const float*)d_in[2];
    const float* in_proj_b  = (const float*)d_in[3];
    const float* out_proj_w = (const float*)d_in[4];
    const float* out_proj_b = (const float*)d_in[5];
    const float* lin1_w     = (const float*)d_in[6];
    const float* lin1_b     = (const float*)d_in[7];
    const float* lin2_w     = (const float*)d_in[8];
    const float* lin2_b     = (const float*)d_in[9];
    const float* ln1_w      = (const float*)d_in[10];
    const float* ln1_b      = (const float*)d_in[11];
    const float* ln2_w      = (const float*)d_in[12];
    const float* ln2_b      = (const float*)d_in[13];
    const float* rel_emb    = (const float*)d_in[14];

    char* ws = (char*)d_ws;
    size_t off = 0;
    auto alloc = [&](size_t bytes) {
        char* p = ws + off;
        off += (bytes + 255) / 256 * 256;
        return (void*)p;
    };
    float* bias_tab       = (float*)alloc((2 * S_LEN - 1) * NHEAD * 4);
    __hip_bfloat16* wqkvb = (__hip_bfloat16*)alloc((size_t)3 * DMODEL * DMODEL * 2);
    __hip_bfloat16* wob   = (__hip_bfloat16*)alloc((size_t)DMODEL * DMODEL * 2);
    __hip_bfloat16* w1b   = (__hip_bfloat16*)alloc((size_t)DFF * DMODEL * 2);
    __hip_bfloat16* w2b   = (__hip_bfloat16*)alloc((size_t)DMODEL * DFF * 2);
    __hip_bfloat16* xb    = (__hip_bfloat16*)alloc((size_t)NROWS * DMODEL * 2);
    __hip_bfloat16* qkvb  = (__hip_bfloat16*)alloc((size_t)3 * 64 * S_LEN * HDIM * 2);
    __hip_bfloat16* o     = (__hip_bfloat16*)alloc((size_t)NROWS * DMODEL * 2);
    float* tmp            = (float*)alloc((size_t)NROWS * DMODEL * 4);
    float* yf             = (float*)alloc((size_t)NROWS * DMODEL * 4);
    __hip_bfloat16* yb    = (__hip_bfloat16*)alloc((size_t)NROWS * DMODEL * 2);
    __hip_bfloat16* ffb   = (__hip_bfloat16*)alloc((size_t)NROWS * DFF * 2);

    float* out = (float*)d_out;

    // 0. casts + bias table
    cast_kernel<<<dim3(3 * DMODEL * DMODEL / 1024), 256, 0, stream>>>(in_proj_w, wqkvb, 3 * DMODEL * DMODEL);
    cast_kernel<<<dim3(DMODEL * DMODEL / 1024), 256, 0, stream>>>(out_proj_w, wob, DMODEL * DMODEL);
    cast_kernel<<<dim3(DFF * DMODEL / 1024), 256, 0, stream>>>(lin1_w, w1b, DFF * DMODEL);
    cast_kernel<<<dim3(DMODEL * DFF / 1024), 256, 0, stream>>>(lin2_w, w2b, DMODEL * DFF);
    cast_kernel<<<dim3(NROWS * DMODEL / 1024), 256, 0, stream>>>(x, xb, NROWS * DMODEL);
    bias_table_kernel<<<dim3(8), 256, 0, stream>>>(rel_emb, bias_tab);

    // 1. qkv projection -> [sect][bh][s][d] bf16
    gemm_tile<2, false, 128><<<dim3(12, 64), 256, 0, stream>>>(
        xb, wqkvb, in_proj_b, qkvb, NROWS, 3 * DMODEL, DMODEL);

    // 2. MFMA flash attention -> o [(s*8+b)][512] bf16
    attn_mfma<<<dim3(S_LEN / 64, BATCH * NHEAD), 256, 0, stream>>>(
        qkvb, attn_mask, bias_tab, o);

    // 3. tmp = o @ out_proj_w^T + out_proj_b         f32
    gemm_tile<0, false, 64><<<dim3(8, 64), 256, 0, stream>>>(
        o, wob, out_proj_b, tmp, NROWS, DMODEL, DMODEL);

    // 4. y = LN(x + tmp)
    ln_kernel<<<dim3(NROWS), 64, 0, stream>>>(x, tmp, ln1_w, ln1_b, yf, yb);

    // 5. ff = relu(y @ lin1_w^T + lin1_b)            bf16
    gemm_tile<1, true, 128><<<dim3(16, 64), 256, 0, stream>>>(
        yb, w1b, lin1_b, ffb, NROWS, DFF, DMODEL);

    // 6. tmp = ff @ lin2_w^T + lin2_b                f32
    gemm_tile<0, false, 64><<<dim3(8, 64), 256, 0, stream>>>(
        ffb, w2b, lin2_b, tmp, NROWS, DMODEL, DFF);

    // 7. out = LN(y + tmp)                           f32
    ln_kernel<<<dim3(NROWS), 64, 0, stream>>>(yf, tmp, ln2_w, ln2_b, out, nullptr);
}